// Round 9
// baseline (194.501 us; speedup 1.0000x reference)
//
#include <hip/hip_runtime.h>
#include <math.h>

// Problem constants: B=128, N=512, PD=512, E=64, gamma=1
#define Bb   128
#define Nn   512
#define Ee   64
#define NCr  192
#define NR2  384      // stacked q+r chains
#define CGIT 22

typedef float vf4 __attribute__((ext_vector_type(4)));

struct CCoef { float cq[5], cr[5], f4, f2; };

__device__ __forceinline__ float wred(float v)
{
    #pragma unroll
    for (int s = 32; s > 0; s >>= 1) v += __shfl_xor(v, s, 64);
    return v;
}

// ---------------------------------------------------------------------------
// k_prep2: partial Y = M @ M. 512 WGs = 64 tiles (64x64) x split-K=8.
// ---------------------------------------------------------------------------
__global__ __launch_bounds__(256) void k_prep2(const float* __restrict__ Mm,
                                               float* __restrict__ Ypart)
{
    __shared__ float As[16][68];
    __shared__ float Bs[16][68];
    const int t  = threadIdx.x;
    const int tx = t & 15, ty = t >> 4;
    const int tile = (int)(blockIdx.x >> 3);
    const int ks   = (int)(blockIdx.x & 7);
    const int r0 = (tile >> 3) * 64;
    const int c0 = (tile & 7) * 64;
    const int kbase = ks * 64;
    const int arow = t >> 2, ac4 = t & 3;

    vf4 acc0 = {0,0,0,0}, acc1 = {0,0,0,0}, acc2 = {0,0,0,0}, acc3 = {0,0,0,0};

    for (int k0 = kbase; k0 < kbase + 64; k0 += 16) {
        vf4 a = *(const vf4*)(Mm + (r0 + arow) * Nn + k0 + 4 * ac4);
        vf4 b = *(const vf4*)(Mm + (k0 + ty) * Nn + c0 + 4 * tx);
        __syncthreads();
        As[4*ac4+0][arow] = a.x; As[4*ac4+1][arow] = a.y;
        As[4*ac4+2][arow] = a.z; As[4*ac4+3][arow] = a.w;
        *(vf4*)&Bs[ty][4*tx] = b;
        __syncthreads();
        #pragma unroll
        for (int kk = 0; kk < 16; ++kk) {
            vf4 av = *(const vf4*)&As[kk][4*ty];
            vf4 bv = *(const vf4*)&Bs[kk][4*tx];
            acc0 += bv * av.x; acc1 += bv * av.y;
            acc2 += bv * av.z; acc3 += bv * av.w;
        }
    }
    float* yp = Ypart + ks * (Nn * Nn) + (r0 + 4*ty) * Nn + c0 + 4*tx;
    *(vf4*)(yp)        = acc0;
    *(vf4*)(yp + Nn)   = acc1;
    *(vf4*)(yp + 2*Nn) = acc2;
    *(vf4*)(yp + 3*Nn) = acc3;
}

// ---------------------------------------------------------------------------
// k_red: Y = sum of 8 split-K partials (fixed order, deterministic).
// ---------------------------------------------------------------------------
__global__ __launch_bounds__(256) void k_red(const float* __restrict__ Ypart,
                                             float* __restrict__ Y)
{
    const int i4 = (int)blockIdx.x * 256 + threadIdx.x;
    vf4 s = {0,0,0,0};
    #pragma unroll
    for (int ks = 0; ks < 8; ++ks)
        s += ((const vf4*)(Ypart + ks * (Nn * Nn)))[i4];
    ((vf4*)Y)[i4] = s;
}

// ---------------------------------------------------------------------------
// k_build: v0 = [X-P | A0^T] (192x512); B1s = [cq4*v0 ; cr4*v0] (384x512);
// B2s = 0. Grid 384 x 256.
// ---------------------------------------------------------------------------
__global__ __launch_bounds__(256) void k_build(
    const float* __restrict__ x, const float* __restrict__ p,
    const float* __restrict__ A0,
    float* __restrict__ v0, float* __restrict__ B1s, float* __restrict__ B2s,
    float cq4, float cr4)
{
    const int i = (int)blockIdx.x * 256 + threadIdx.x;   // 0..98303
    const int row = i >> 9;
    float v = (row < Bb) ? (x[i] - p[i]) : A0[i - Bb * Nn];
    v0[i] = v;
    B1s[i]            = cq4 * v;
    B1s[i + NCr * Nn] = cr4 * v;
    B2s[i]            = 0.f;
    B2s[i + NCr * Nn] = 0.f;
}

// ---------------------------------------------------------------------------
// k_ymul: partial C = src(rows x 512) @ mat(512x512). Tile 64x64, split-K=8.
// Grid = (rows/64) * 8cb * 8ks. Partials at fixed 384-row stride slabs.
// ---------------------------------------------------------------------------
__global__ __launch_bounds__(256) void k_ymul(const float* __restrict__ src,
                                              const float* __restrict__ mat,
                                              float* __restrict__ part)
{
    __shared__ float As[16][68];
    __shared__ float Bs[16][68];
    const int t  = threadIdx.x;
    const int tx = t & 15, ty = t >> 4;
    const int wg = (int)blockIdx.x;
    const int ks  = wg & 7;
    const int cb  = (wg >> 3) & 7;
    const int rbk = wg >> 6;
    const int r0 = rbk * 64, c0 = cb * 64, kbase = ks * 64;
    const int arow = t >> 2, ac4 = t & 3;

    vf4 acc0 = {0,0,0,0}, acc1 = {0,0,0,0}, acc2 = {0,0,0,0}, acc3 = {0,0,0,0};

    for (int k0 = kbase; k0 < kbase + 64; k0 += 16) {
        vf4 a = *(const vf4*)(src + (r0 + arow) * Nn + k0 + 4 * ac4);
        vf4 b = *(const vf4*)(mat + (k0 + ty) * Nn + c0 + 4 * tx);
        __syncthreads();
        As[4*ac4+0][arow] = a.x; As[4*ac4+1][arow] = a.y;
        As[4*ac4+2][arow] = a.z; As[4*ac4+3][arow] = a.w;
        *(vf4*)&Bs[ty][4*tx] = b;
        __syncthreads();
        #pragma unroll
        for (int kk = 0; kk < 16; ++kk) {
            vf4 av = *(const vf4*)&As[kk][4*ty];
            vf4 bv = *(const vf4*)&Bs[kk][4*tx];
            acc0 += bv * av.x; acc1 += bv * av.y;
            acc2 += bv * av.z; acc3 += bv * av.w;
        }
    }
    float* yp = part + ks * (NR2 * Nn) + (r0 + 4*ty) * Nn + c0 + 4*tx;
    *(vf4*)(yp)        = acc0;
    *(vf4*)(yp + Nn)   = acc1;
    *(vf4*)(yp + 2*Nn) = acc2;
    *(vf4*)(yp + 3*Nn) = acc3;
}

// ---------------------------------------------------------------------------
// k_upd: combine 8 split-K partials (both chains) + Clenshaw step.
// step<3: b_new = c_j*v0 + f4*(Y b1) - 2 b1 - b2 ; rotate.
// final:  F     = c_0*v0 + f2*(Y b1) - b1 - b2.
// Grid 384 x 256 (one thread per (row,col), handles q and r chains).
// ---------------------------------------------------------------------------
__global__ __launch_bounds__(256) void k_upd(
    const float* __restrict__ part, const float* __restrict__ v0,
    float* __restrict__ B1s, float* __restrict__ B2s,
    float cqj, float crj, float fscale, int finalstep)
{
    const int i = (int)blockIdx.x * 256 + threadIdx.x;   // 0..98303
    float yvq = 0.f, yvr = 0.f;
    #pragma unroll
    for (int ks = 0; ks < 8; ++ks) {
        yvq += part[ks * (NR2 * Nn) + i];
        yvr += part[ks * (NR2 * Nn) + NCr * Nn + i];
    }
    float v  = v0[i];
    float q1 = B1s[i], q2 = B2s[i];
    float r1 = B1s[i + NCr * Nn], r2 = B2s[i + NCr * Nn];
    if (!finalstep) {
        float bnq = cqj * v + fscale * yvq - 2.f * q1 - q2;
        float bnr = crj * v + fscale * yvr - 2.f * r1 - r2;
        B2s[i] = q1;              B1s[i] = bnq;
        B2s[i + NCr * Nn] = r1;   B1s[i + NCr * Nn] = bnr;
    } else {
        float Fq = cqj * v + fscale * yvq - q1 - q2;
        float Fr = crj * v + fscale * yvr - r1 - r2;
        B1s[i] = Fq;              B1s[i + NCr * Nn] = Fr;
    }
}

// ---------------------------------------------------------------------------
// k_ufin: u = Fq + sum of 8 partials of (M @ Fr). Grid 192 x 512-elems /256.
// ---------------------------------------------------------------------------
__global__ __launch_bounds__(256) void k_ufin(
    const float* __restrict__ part, const float* __restrict__ B1s,
    float* __restrict__ u_g)
{
    const int i = (int)blockIdx.x * 256 + threadIdx.x;   // 0..98303
    float s = B1s[i];                                    // Fq
    #pragma unroll
    for (int ks = 0; ks < 8; ++ks)
        s += part[ks * (NR2 * Nn) + i];
    u_g[i] = s;
}

// ---------------------------------------------------------------------------
// k_small: su[e][j] (64 x 192): j<64 -> S[e][j] = A0[e,:]·u'[128+j,:]
//                               j>=64 -> rhs[e][j-64] = A0[e,:]·u'[j-64,:] + c[e]
// ---------------------------------------------------------------------------
__global__ __launch_bounds__(256) void k_small(
    const float* __restrict__ A0, const float* __restrict__ u,
    const float* __restrict__ c, float* __restrict__ su)
{
    __shared__ float As[16][33];
    __shared__ float Us[16][33];
    int t  = threadIdx.x;
    int tx = t & 15, ty = t >> 4;
    int e0 = ((int)blockIdx.x / 12) * 16;
    int j0 = ((int)blockIdx.x % 12) * 16;
    float acc = 0.f;

    for (int k0 = 0; k0 < Nn; k0 += 32) {
        #pragma unroll
        for (int i = 0; i < 2; ++i) {
            int ii = t + i * 256;
            int rr = ii >> 5, cc = ii & 31;
            As[rr][cc] = A0[(e0 + rr) * Nn + k0 + cc];
            int j_ = j0 + rr;
            int urow = (j_ < 64) ? (Bb + j_) : (j_ - 64);
            Us[rr][cc] = u[urow * Nn + k0 + cc];
        }
        __syncthreads();
        #pragma unroll
        for (int kk = 0; kk < 32; ++kk)
            acc += As[ty][kk] * Us[tx][kk];
        __syncthreads();
    }
    int e = e0 + ty, j = j0 + tx;
    su[e * NCr + j] = acc + ((j >= 64) ? c[e] : 0.f);
}

// ---------------------------------------------------------------------------
// k_lam_final: CG on S (64x64 SPD) for 128 columns, 1 wave/column, then
// out[b] = T_b - V * Lambda_b.  16 WGs x 512 thr.
// ---------------------------------------------------------------------------
__global__ __launch_bounds__(512) void k_lam_final(
    const float* __restrict__ u_g, const float* __restrict__ su,
    float* __restrict__ out)
{
    __shared__ float Sm[64][65];
    __shared__ float pb[8][64];
    const int t = threadIdx.x, w = t >> 6, lane = t & 63;

    for (int i = t; i < 64 * 64; i += 512)
        Sm[i >> 6][i & 63] = su[(i >> 6) * NCr + (i & 63)];
    __syncthreads();

    const int b = (int)blockIdx.x * 8 + w;
    float srow[64];
    #pragma unroll
    for (int k = 0; k < 64; ++k) srow[k] = Sm[lane][k];

    float rhs = su[lane * NCr + 64 + b];
    float xv = 0.f, rv = rhs, pv = rv;
    float rr = wred(rv * rv);
    for (int itc = 0; itc < CGIT; ++itc) {
        pb[w][lane] = pv;
        float q = 0.f;
        #pragma unroll
        for (int k = 0; k < 64; ++k) q += srow[k] * pb[w][k];
        float pq = wred(pv * q);
        float alpha = rr / fmaxf(pq, 1e-30f);
        xv += alpha * pv;
        rv -= alpha * q;
        float rr2 = wred(rv * rv);
        float beta = rr2 / fmaxf(rr, 1e-30f);
        rr = rr2;
        pv = rv + beta * pv;
    }
    pb[w][lane] = xv;

    #pragma unroll
    for (int i = 0; i < 8; ++i) {
        int n = lane + 64 * i;
        float acc = u_g[b * Nn + n];
        #pragma unroll 4
        for (int e = 0; e < Ee; ++e)
            acc -= pb[w][e] * u_g[(Bb + e) * Nn + n];
        out[b * Nn + n] = acc;
    }
}

// ---------------------------------------------------------------------------
extern "C" void kernel_launch(void* const* d_in, const int* in_sizes, int n_in,
                              void* d_out, int out_size, void* d_ws, size_t ws_size,
                              hipStream_t stream)
{
    const float* x     = (const float*)d_in[0];
    const float* parms = (const float*)d_in[1];
    const float* Mm    = (const float*)d_in[2];
    const float* A0    = (const float*)d_in[3];
    // d_in[4] = B0 unused (F at zeros -> only c survives)
    const float* c     = (const float*)d_in[5];
    float* out = (float*)d_out;

    float* ws    = (float*)d_ws;
    float* Ypart = ws;                                   // 8 * 512*512
    float* Y     = Ypart + 8 * Nn * Nn;                  // 512*512
    float* Zpart = Y + Nn * Nn;                          // 8 * 384*512
    float* v0    = Zpart + 8 * NR2 * Nn;                 // 192*512
    float* B1s   = v0 + NCr * Nn;                        // 384*512
    float* B2s   = B1s + NR2 * Nn;                       // 384*512
    float* u_g   = B2s + NR2 * Nn;                       // 192*512
    float* su    = u_g + NCr * Nn;                       // 64*192

    // ---- host: degree-9 Chebyshev poly for 1/h on [1, 3.12], even/odd split,
    // converted to Chebyshev basis on y = m^2 in [0, ymax] (all double).
    const double aa = 1.0, bbound = 3.12;
    const double th = 0.5 * (bbound + aa), de = 0.5 * (bbound - aa), sg = th / de;
    double rp[16] = {0}, dp[16] = {0}, xp[16] = {0}, hd[16];
    rp[0] = 1.0; dp[0] = 1.0 / th; xp[0] = 1.0 / th;
    double rho_prev = 1.0 / sg;
    for (int k = 1; k <= 9; ++k) {
        double rho = 1.0 / (2.0 * sg - rho_prev);
        double C1 = rho * rho_prev, C2 = 2.0 * rho / de;
        for (int i = 15; i >= 1; --i) hd[i] = dp[i - 1];
        hd[0] = 0.0;
        for (int i = 0; i < 16; ++i) {
            rp[i] -= hd[i];
            dp[i] = C1 * dp[i] + C2 * rp[i];
            xp[i] += dp[i];
        }
        rho_prev = rho;
    }
    // substitute h = 1 + m/2
    double pm[16] = {0};
    for (int k = 0; k <= 9; ++k) {
        double term[16] = {0}; term[0] = 1.0;
        for (int e = 0; e < k; ++e) {
            double nt[16] = {0};
            for (int i = 0; i <= e; ++i) { nt[i] += term[i]; nt[i + 1] += 0.5 * term[i]; }
            for (int i = 0; i <= e + 1; ++i) term[i] = nt[i];
        }
        for (int i = 0; i <= k; ++i) pm[i] += xp[k] * term[i];
    }
    double qm[8] = {0}, rm[8] = {0};
    for (int jj = 0; jj < 5; ++jj) { qm[jj] = pm[2 * jj]; rm[jj] = pm[2 * jj + 1]; }
    const double mmax = 2.0 * (bbound - 1.0);
    const double ymax = mmax * mmax;
    double cq[5] = {0}, cr[5] = {0};
    const int NP = 64;
    for (int i = 0; i < NP; ++i) {
        double thn = M_PI * (i + 0.5) / NP;
        double s = cos(thn);
        double y = 0.5 * ymax * (s + 1.0);
        double vq = 0, vr = 0;
        for (int d2 = 4; d2 >= 0; --d2) { vq = vq * y + qm[d2]; vr = vr * y + rm[d2]; }
        for (int jj = 0; jj < 5; ++jj) {
            cq[jj] += (2.0 / NP) * vq * cos(jj * thn);
            cr[jj] += (2.0 / NP) * vr * cos(jj * thn);
        }
    }
    cq[0] *= 0.5; cr[0] *= 0.5;
    CCoef cf;
    for (int jj = 0; jj < 5; ++jj) { cf.cq[jj] = (float)cq[jj]; cf.cr[jj] = (float)cr[jj]; }
    cf.f4 = (float)(4.0 / ymax);
    cf.f2 = (float)(2.0 / ymax);

    // ---- launch chain (graph-captured): everything full-chip, no grid syncs
    hipLaunchKernelGGL(k_prep2, dim3(512), dim3(256), 0, stream, Mm, Ypart);
    hipLaunchKernelGGL(k_red,   dim3(256), dim3(256), 0, stream, Ypart, Y);
    hipLaunchKernelGGL(k_build, dim3(384), dim3(256), 0, stream,
                       x, parms, A0, v0, B1s, B2s, cf.cq[4], cf.cr[4]);

    for (int step = 0; step < 4; ++step) {
        hipLaunchKernelGGL(k_ymul, dim3(NR2 / 64 * 64), dim3(256), 0, stream,
                           B1s, Y, Zpart);
        if (step < 3) {
            hipLaunchKernelGGL(k_upd, dim3(384), dim3(256), 0, stream,
                               Zpart, v0, B1s, B2s,
                               cf.cq[3 - step], cf.cr[3 - step], cf.f4, 0);
        } else {
            hipLaunchKernelGGL(k_upd, dim3(384), dim3(256), 0, stream,
                               Zpart, v0, B1s, B2s,
                               cf.cq[0], cf.cr[0], cf.f2, 1);
        }
    }

    // final M-pass on Fr (rows 192..384 of B1s), then u = Fq + M*Fr
    hipLaunchKernelGGL(k_ymul, dim3(192), dim3(256), 0, stream,
                       B1s + NCr * Nn, Mm, Zpart);
    hipLaunchKernelGGL(k_ufin, dim3(384), dim3(256), 0, stream, Zpart, B1s, u_g);

    hipLaunchKernelGGL(k_small,     dim3(48), dim3(256), 0, stream, A0, u_g, c, su);
    hipLaunchKernelGGL(k_lam_final, dim3(16), dim3(512), 0, stream, u_g, su, out);
}

// Round 10
// 193.175 us; speedup vs baseline: 1.0069x; 1.0069x over previous
//
#include <hip/hip_runtime.h>
#include <math.h>

// Problem constants: B=128, N=512, PD=512, E=64, gamma=1
#define Bb   128
#define Nn   512
#define Ee   64
#define NCr  192
#define NR2  384      // stacked q+r chains
#define CGIT 22

typedef float vf4 __attribute__((ext_vector_type(4)));

struct CCoef { float cq[5], cr[5], f4, f2; };

__device__ __forceinline__ float wred(float v)
{
    #pragma unroll
    for (int s = 32; s > 0; s >>= 1) v += __shfl_xor(v, s, 64);
    return v;
}

// ---------------------------------------------------------------------------
// k_prep2: partial Y = M @ M. 512 WGs = 64 tiles (64x64) x split-K=8.
// ---------------------------------------------------------------------------
__global__ __launch_bounds__(256) void k_prep2(const float* __restrict__ Mm,
                                               float* __restrict__ Ypart)
{
    __shared__ float As[16][68];
    __shared__ float Bs[16][68];
    const int t  = threadIdx.x;
    const int tx = t & 15, ty = t >> 4;
    const int tile = (int)(blockIdx.x >> 3);
    const int ks   = (int)(blockIdx.x & 7);
    const int r0 = (tile >> 3) * 64;
    const int c0 = (tile & 7) * 64;
    const int kbase = ks * 64;
    const int arow = t >> 2, ac4 = t & 3;

    vf4 acc0 = {0,0,0,0}, acc1 = {0,0,0,0}, acc2 = {0,0,0,0}, acc3 = {0,0,0,0};

    for (int k0 = kbase; k0 < kbase + 64; k0 += 16) {
        vf4 a = *(const vf4*)(Mm + (r0 + arow) * Nn + k0 + 4 * ac4);
        vf4 b = *(const vf4*)(Mm + (k0 + ty) * Nn + c0 + 4 * tx);
        __syncthreads();
        As[4*ac4+0][arow] = a.x; As[4*ac4+1][arow] = a.y;
        As[4*ac4+2][arow] = a.z; As[4*ac4+3][arow] = a.w;
        *(vf4*)&Bs[ty][4*tx] = b;
        __syncthreads();
        #pragma unroll
        for (int kk = 0; kk < 16; ++kk) {
            vf4 av = *(const vf4*)&As[kk][4*ty];
            vf4 bv = *(const vf4*)&Bs[kk][4*tx];
            acc0 += bv * av.x; acc1 += bv * av.y;
            acc2 += bv * av.z; acc3 += bv * av.w;
        }
    }
    float* yp = Ypart + ks * (Nn * Nn) + (r0 + 4*ty) * Nn + c0 + 4*tx;
    *(vf4*)(yp)        = acc0;
    *(vf4*)(yp + Nn)   = acc1;
    *(vf4*)(yp + 2*Nn) = acc2;
    *(vf4*)(yp + 3*Nn) = acc3;
}

// ---------------------------------------------------------------------------
// k_red: Y = sum of 8 split-K partials (fixed order, deterministic).
// ---------------------------------------------------------------------------
__global__ __launch_bounds__(256) void k_red(const float* __restrict__ Ypart,
                                             float* __restrict__ Y)
{
    const int i4 = (int)blockIdx.x * 256 + threadIdx.x;
    vf4 s = {0,0,0,0};
    #pragma unroll
    for (int ks = 0; ks < 8; ++ks)
        s += ((const vf4*)(Ypart + ks * (Nn * Nn)))[i4];
    ((vf4*)Y)[i4] = s;
}

// ---------------------------------------------------------------------------
// k_build: v0 = [X-P | A0^T] (192x512); B1s = [cq4*v0 ; cr4*v0]; B2s = 0.
// ---------------------------------------------------------------------------
__global__ __launch_bounds__(256) void k_build(
    const float* __restrict__ x, const float* __restrict__ p,
    const float* __restrict__ A0,
    float* __restrict__ v0, float* __restrict__ B1s, float* __restrict__ B2s,
    float cq4, float cr4)
{
    const int i = (int)blockIdx.x * 256 + threadIdx.x;   // 0..98303
    const int row = i >> 9;
    float v = (row < Bb) ? (x[i] - p[i]) : A0[i - Bb * Nn];
    v0[i] = v;
    B1s[i]            = cq4 * v;
    B1s[i + NCr * Nn] = cr4 * v;
    B2s[i]            = 0.f;
    B2s[i + NCr * Nn] = 0.f;
}

// ---------------------------------------------------------------------------
// k_ymul: partial C = src(rows x 512) @ mat(512x512). Tile 64x64, split-K=8.
// ---------------------------------------------------------------------------
__global__ __launch_bounds__(256) void k_ymul(const float* __restrict__ src,
                                              const float* __restrict__ mat,
                                              float* __restrict__ part)
{
    __shared__ float As[16][68];
    __shared__ float Bs[16][68];
    const int t  = threadIdx.x;
    const int tx = t & 15, ty = t >> 4;
    const int wg = (int)blockIdx.x;
    const int ks  = wg & 7;
    const int cb  = (wg >> 3) & 7;
    const int rbk = wg >> 6;
    const int r0 = rbk * 64, c0 = cb * 64, kbase = ks * 64;
    const int arow = t >> 2, ac4 = t & 3;

    vf4 acc0 = {0,0,0,0}, acc1 = {0,0,0,0}, acc2 = {0,0,0,0}, acc3 = {0,0,0,0};

    for (int k0 = kbase; k0 < kbase + 64; k0 += 16) {
        vf4 a = *(const vf4*)(src + (r0 + arow) * Nn + k0 + 4 * ac4);
        vf4 b = *(const vf4*)(mat + (k0 + ty) * Nn + c0 + 4 * tx);
        __syncthreads();
        As[4*ac4+0][arow] = a.x; As[4*ac4+1][arow] = a.y;
        As[4*ac4+2][arow] = a.z; As[4*ac4+3][arow] = a.w;
        *(vf4*)&Bs[ty][4*tx] = b;
        __syncthreads();
        #pragma unroll
        for (int kk = 0; kk < 16; ++kk) {
            vf4 av = *(const vf4*)&As[kk][4*ty];
            vf4 bv = *(const vf4*)&Bs[kk][4*tx];
            acc0 += bv * av.x; acc1 += bv * av.y;
            acc2 += bv * av.z; acc3 += bv * av.w;
        }
    }
    float* yp = part + ks * (NR2 * Nn) + (r0 + 4*ty) * Nn + c0 + 4*tx;
    *(vf4*)(yp)        = acc0;
    *(vf4*)(yp + Nn)   = acc1;
    *(vf4*)(yp + 2*Nn) = acc2;
    *(vf4*)(yp + 3*Nn) = acc3;
}

// ---------------------------------------------------------------------------
// k_upd: combine 8 split-K partials (both chains) + Clenshaw step.
// ---------------------------------------------------------------------------
__global__ __launch_bounds__(256) void k_upd(
    const float* __restrict__ part, const float* __restrict__ v0,
    float* __restrict__ B1s, float* __restrict__ B2s,
    float cqj, float crj, float fscale, int finalstep)
{
    const int i = (int)blockIdx.x * 256 + threadIdx.x;   // 0..98303
    float yvq = 0.f, yvr = 0.f;
    #pragma unroll
    for (int ks = 0; ks < 8; ++ks) {
        yvq += part[ks * (NR2 * Nn) + i];
        yvr += part[ks * (NR2 * Nn) + NCr * Nn + i];
    }
    float v  = v0[i];
    float q1 = B1s[i], q2 = B2s[i];
    float r1 = B1s[i + NCr * Nn], r2 = B2s[i + NCr * Nn];
    if (!finalstep) {
        float bnq = cqj * v + fscale * yvq - 2.f * q1 - q2;
        float bnr = crj * v + fscale * yvr - 2.f * r1 - r2;
        B2s[i] = q1;              B1s[i] = bnq;
        B2s[i + NCr * Nn] = r1;   B1s[i + NCr * Nn] = bnr;
    } else {
        float Fq = cqj * v + fscale * yvq - q1 - q2;
        float Fr = crj * v + fscale * yvr - r1 - r2;
        B1s[i] = Fq;              B1s[i + NCr * Nn] = Fr;
    }
}

// ---------------------------------------------------------------------------
// k_ufin: u = Fq + sum of 8 partials of (M @ Fr).
// ---------------------------------------------------------------------------
__global__ __launch_bounds__(256) void k_ufin(
    const float* __restrict__ part, const float* __restrict__ B1s,
    float* __restrict__ u_g)
{
    const int i = (int)blockIdx.x * 256 + threadIdx.x;   // 0..98303
    float s = B1s[i];                                    // Fq
    #pragma unroll
    for (int ks = 0; ks < 8; ++ks)
        s += part[ks * (NR2 * Nn) + i];
    u_g[i] = s;
}

// ---------------------------------------------------------------------------
// k_small: su[e][j] (64 x 192): j<64 -> S[e][j] = A0[e,:]·u'[128+j,:]
//                               j>=64 -> rhs[e][j-64] = A0[e,:]·u'[j-64,:] + c[e]
// ---------------------------------------------------------------------------
__global__ __launch_bounds__(256) void k_small(
    const float* __restrict__ A0, const float* __restrict__ u,
    const float* __restrict__ c, float* __restrict__ su)
{
    __shared__ float As[16][33];
    __shared__ float Us[16][33];
    int t  = threadIdx.x;
    int tx = t & 15, ty = t >> 4;
    int e0 = ((int)blockIdx.x / 12) * 16;
    int j0 = ((int)blockIdx.x % 12) * 16;
    float acc = 0.f;

    for (int k0 = 0; k0 < Nn; k0 += 32) {
        #pragma unroll
        for (int i = 0; i < 2; ++i) {
            int ii = t + i * 256;
            int rr = ii >> 5, cc = ii & 31;
            As[rr][cc] = A0[(e0 + rr) * Nn + k0 + cc];
            int j_ = j0 + rr;
            int urow = (j_ < 64) ? (Bb + j_) : (j_ - 64);
            Us[rr][cc] = u[urow * Nn + k0 + cc];
        }
        __syncthreads();
        #pragma unroll
        for (int kk = 0; kk < 32; ++kk)
            acc += As[ty][kk] * Us[tx][kk];
        __syncthreads();
    }
    int e = e0 + ty, j = j0 + tx;
    su[e * NCr + j] = acc + ((j >= 64) ? c[e] : 0.f);
}

// ---------------------------------------------------------------------------
// k_lam2: CG on S (64x64 SPD), ONE WAVE PER COLUMN, 64 WGs x 128 thr.
// __launch_bounds__(128,1) -> register allocator may use ~full VGPR file, so
// srow[64] stays register-resident (the old 16-WG/512-thr version spilled to
// scratch at VGPR_Count=48 and cost 58 us). S staged via LDS; p broadcast via
// wave-private LDS (in-order DS, no barriers in the loop). Fused correction:
// out[b] = T_b - V^T Lambda_b.
// ---------------------------------------------------------------------------
__global__ __launch_bounds__(128, 1) void k_lam2(
    const float* __restrict__ u_g, const float* __restrict__ su,
    float* __restrict__ out)
{
    __shared__ float Sm[64 * 65];
    __shared__ float pb[2][64];
    const int t = threadIdx.x, w = t >> 6, lane = t & 63;

    for (int i = t; i < 64 * 64; i += 128)
        Sm[(i >> 6) * 65 + (i & 63)] = su[(i >> 6) * NCr + (i & 63)];
    __syncthreads();

    const int b = (int)blockIdx.x * 2 + w;     // column 0..127
    float srow[64];
    #pragma unroll
    for (int k = 0; k < 64; ++k) srow[k] = Sm[lane * 65 + k];

    float rhs = su[lane * NCr + 64 + b];
    float xv = 0.f, rv = rhs, pv = rv;
    float rr = wred(rv * rv);
    for (int itc = 0; itc < CGIT; ++itc) {
        pb[w][lane] = pv;                      // wave-private, DS in-order
        float q = 0.f;
        #pragma unroll
        for (int k = 0; k < 64; ++k) q += srow[k] * pb[w][k];
        float pq = wred(pv * q);
        float alpha = rr / fmaxf(pq, 1e-30f);
        xv += alpha * pv;
        rv -= alpha * q;
        float rr2 = wred(rv * rv);
        float beta = rr2 / fmaxf(rr, 1e-30f);
        rr = rr2;
        pv = rv + beta * pv;
    }
    pb[w][lane] = xv;                          // broadcast Lambda[:,b] in-wave

    #pragma unroll
    for (int i = 0; i < 8; ++i) {
        int n = lane + 64 * i;
        float acc = u_g[b * Nn + n];
        #pragma unroll 4
        for (int e = 0; e < Ee; ++e)
            acc -= pb[w][e] * u_g[(Bb + e) * Nn + n];
        out[b * Nn + n] = acc;
    }
}

// ---------------------------------------------------------------------------
extern "C" void kernel_launch(void* const* d_in, const int* in_sizes, int n_in,
                              void* d_out, int out_size, void* d_ws, size_t ws_size,
                              hipStream_t stream)
{
    const float* x     = (const float*)d_in[0];
    const float* parms = (const float*)d_in[1];
    const float* Mm    = (const float*)d_in[2];
    const float* A0    = (const float*)d_in[3];
    // d_in[4] = B0 unused (F at zeros -> only c survives)
    const float* c     = (const float*)d_in[5];
    float* out = (float*)d_out;

    float* ws    = (float*)d_ws;
    float* Ypart = ws;                                   // 8 * 512*512
    float* Y     = Ypart + 8 * Nn * Nn;                  // 512*512
    float* Zpart = Y + Nn * Nn;                          // 8 * 384*512
    float* v0    = Zpart + 8 * NR2 * Nn;                 // 192*512
    float* B1s   = v0 + NCr * Nn;                        // 384*512
    float* B2s   = B1s + NR2 * Nn;                       // 384*512
    float* u_g   = B2s + NR2 * Nn;                       // 192*512
    float* su    = u_g + NCr * Nn;                       // 64*192

    // ---- host: degree-9 Chebyshev poly for 1/h on [1, 3.12], even/odd split,
    // converted to Chebyshev basis on y = m^2 in [0, ymax] (all double).
    const double aa = 1.0, bbound = 3.12;
    const double th = 0.5 * (bbound + aa), de = 0.5 * (bbound - aa), sg = th / de;
    double rp[16] = {0}, dp[16] = {0}, xp[16] = {0}, hd[16];
    rp[0] = 1.0; dp[0] = 1.0 / th; xp[0] = 1.0 / th;
    double rho_prev = 1.0 / sg;
    for (int k = 1; k <= 9; ++k) {
        double rho = 1.0 / (2.0 * sg - rho_prev);
        double C1 = rho * rho_prev, C2 = 2.0 * rho / de;
        for (int i = 15; i >= 1; --i) hd[i] = dp[i - 1];
        hd[0] = 0.0;
        for (int i = 0; i < 16; ++i) {
            rp[i] -= hd[i];
            dp[i] = C1 * dp[i] + C2 * rp[i];
            xp[i] += dp[i];
        }
        rho_prev = rho;
    }
    // substitute h = 1 + m/2
    double pm[16] = {0};
    for (int k = 0; k <= 9; ++k) {
        double term[16] = {0}; term[0] = 1.0;
        for (int e = 0; e < k; ++e) {
            double nt[16] = {0};
            for (int i = 0; i <= e; ++i) { nt[i] += term[i]; nt[i + 1] += 0.5 * term[i]; }
            for (int i = 0; i <= e + 1; ++i) term[i] = nt[i];
        }
        for (int i = 0; i <= k; ++i) pm[i] += xp[k] * term[i];
    }
    double qm[8] = {0}, rm[8] = {0};
    for (int jj = 0; jj < 5; ++jj) { qm[jj] = pm[2 * jj]; rm[jj] = pm[2 * jj + 1]; }
    const double mmax = 2.0 * (bbound - 1.0);
    const double ymax = mmax * mmax;
    double cq[5] = {0}, cr[5] = {0};
    const int NP = 64;
    for (int i = 0; i < NP; ++i) {
        double thn = M_PI * (i + 0.5) / NP;
        double s = cos(thn);
        double y = 0.5 * ymax * (s + 1.0);
        double vq = 0, vr = 0;
        for (int d2 = 4; d2 >= 0; --d2) { vq = vq * y + qm[d2]; vr = vr * y + rm[d2]; }
        for (int jj = 0; jj < 5; ++jj) {
            cq[jj] += (2.0 / NP) * vq * cos(jj * thn);
            cr[jj] += (2.0 / NP) * vr * cos(jj * thn);
        }
    }
    cq[0] *= 0.5; cr[0] *= 0.5;
    CCoef cf;
    for (int jj = 0; jj < 5; ++jj) { cf.cq[jj] = (float)cq[jj]; cf.cr[jj] = (float)cr[jj]; }
    cf.f4 = (float)(4.0 / ymax);
    cf.f2 = (float)(2.0 / ymax);

    // ---- launch chain (graph-captured): everything full-chip, no grid syncs
    hipLaunchKernelGGL(k_prep2, dim3(512), dim3(256), 0, stream, Mm, Ypart);
    hipLaunchKernelGGL(k_red,   dim3(256), dim3(256), 0, stream, Ypart, Y);
    hipLaunchKernelGGL(k_build, dim3(384), dim3(256), 0, stream,
                       x, parms, A0, v0, B1s, B2s, cf.cq[4], cf.cr[4]);

    for (int step = 0; step < 4; ++step) {
        hipLaunchKernelGGL(k_ymul, dim3(NR2 / 64 * 64), dim3(256), 0, stream,
                           B1s, Y, Zpart);
        if (step < 3) {
            hipLaunchKernelGGL(k_upd, dim3(384), dim3(256), 0, stream,
                               Zpart, v0, B1s, B2s,
                               cf.cq[3 - step], cf.cr[3 - step], cf.f4, 0);
        } else {
            hipLaunchKernelGGL(k_upd, dim3(384), dim3(256), 0, stream,
                               Zpart, v0, B1s, B2s,
                               cf.cq[0], cf.cr[0], cf.f2, 1);
        }
    }

    // final M-pass on Fr (rows 192..384 of B1s), then u = Fq + M*Fr
    hipLaunchKernelGGL(k_ymul, dim3(192), dim3(256), 0, stream,
                       B1s + NCr * Nn, Mm, Zpart);
    hipLaunchKernelGGL(k_ufin, dim3(384), dim3(256), 0, stream, Zpart, B1s, u_g);

    hipLaunchKernelGGL(k_small, dim3(48), dim3(256), 0, stream, A0, u_g, c, su);
    hipLaunchKernelGGL(k_lam2,  dim3(64), dim3(128), 0, stream, u_g, su, out);
}

// Round 11
// 179.367 us; speedup vs baseline: 1.0844x; 1.0770x over previous
//
#include <hip/hip_runtime.h>
#include <math.h>

// Problem constants: B=128, N=512, PD=512, E=64, gamma=1
#define Bb   128
#define Nn   512
#define Ee   64
#define NCr  192
#define NR2  384      // stacked q+r chains
#define CGIT 22

typedef float vf4 __attribute__((ext_vector_type(4)));

struct CCoef { float cq[5], cr[5], f4, f2; };

__device__ __forceinline__ float wred(float v)
{
    #pragma unroll
    for (int s = 32; s > 0; s >>= 1) v += __shfl_xor(v, s, 64);
    return v;
}

// ---------------------------------------------------------------------------
// k_prep2: partial Y = M @ M. 512 WGs = 64 tiles (64x64) x split-K=8.
// ---------------------------------------------------------------------------
__global__ __launch_bounds__(256) void k_prep2(const float* __restrict__ Mm,
                                               float* __restrict__ Ypart)
{
    __shared__ float As[16][68];
    __shared__ float Bs[16][68];
    const int t  = threadIdx.x;
    const int tx = t & 15, ty = t >> 4;
    const int tile = (int)(blockIdx.x >> 3);
    const int ks   = (int)(blockIdx.x & 7);
    const int r0 = (tile >> 3) * 64;
    const int c0 = (tile & 7) * 64;
    const int kbase = ks * 64;
    const int arow = t >> 2, ac4 = t & 3;

    vf4 acc0 = {0,0,0,0}, acc1 = {0,0,0,0}, acc2 = {0,0,0,0}, acc3 = {0,0,0,0};

    for (int k0 = kbase; k0 < kbase + 64; k0 += 16) {
        vf4 a = *(const vf4*)(Mm + (r0 + arow) * Nn + k0 + 4 * ac4);
        vf4 b = *(const vf4*)(Mm + (k0 + ty) * Nn + c0 + 4 * tx);
        __syncthreads();
        As[4*ac4+0][arow] = a.x; As[4*ac4+1][arow] = a.y;
        As[4*ac4+2][arow] = a.z; As[4*ac4+3][arow] = a.w;
        *(vf4*)&Bs[ty][4*tx] = b;
        __syncthreads();
        #pragma unroll
        for (int kk = 0; kk < 16; ++kk) {
            vf4 av = *(const vf4*)&As[kk][4*ty];
            vf4 bv = *(const vf4*)&Bs[kk][4*tx];
            acc0 += bv * av.x; acc1 += bv * av.y;
            acc2 += bv * av.z; acc3 += bv * av.w;
        }
    }
    float* yp = Ypart + ks * (Nn * Nn) + (r0 + 4*ty) * Nn + c0 + 4*tx;
    *(vf4*)(yp)        = acc0;
    *(vf4*)(yp + Nn)   = acc1;
    *(vf4*)(yp + 2*Nn) = acc2;
    *(vf4*)(yp + 3*Nn) = acc3;
}

// ---------------------------------------------------------------------------
// k_red: Y = sum of 8 split-K partials (fixed order, deterministic).
// ---------------------------------------------------------------------------
__global__ __launch_bounds__(256) void k_red(const float* __restrict__ Ypart,
                                             float* __restrict__ Y)
{
    const int i4 = (int)blockIdx.x * 256 + threadIdx.x;
    vf4 s = {0,0,0,0};
    #pragma unroll
    for (int ks = 0; ks < 8; ++ks)
        s += ((const vf4*)(Ypart + ks * (Nn * Nn)))[i4];
    ((vf4*)Y)[i4] = s;
}

// ---------------------------------------------------------------------------
// k_build: v0 = [X-P | A0^T] (192x512); B1s = [cq4*v0 ; cr4*v0]; B2s = 0.
// ---------------------------------------------------------------------------
__global__ __launch_bounds__(256) void k_build(
    const float* __restrict__ x, const float* __restrict__ p,
    const float* __restrict__ A0,
    float* __restrict__ v0, float* __restrict__ B1s, float* __restrict__ B2s,
    float cq4, float cr4)
{
    const int i = (int)blockIdx.x * 256 + threadIdx.x;   // 0..98303
    const int row = i >> 9;
    float v = (row < Bb) ? (x[i] - p[i]) : A0[i - Bb * Nn];
    v0[i] = v;
    B1s[i]            = cq4 * v;
    B1s[i + NCr * Nn] = cr4 * v;
    B2s[i]            = 0.f;
    B2s[i + NCr * Nn] = 0.f;
}

// ---------------------------------------------------------------------------
// k_ymul: partial C = src(rows x 512) @ mat(512x512). Tile 64x64, split-K=8.
// ---------------------------------------------------------------------------
__global__ __launch_bounds__(256) void k_ymul(const float* __restrict__ src,
                                              const float* __restrict__ mat,
                                              float* __restrict__ part)
{
    __shared__ float As[16][68];
    __shared__ float Bs[16][68];
    const int t  = threadIdx.x;
    const int tx = t & 15, ty = t >> 4;
    const int wg = (int)blockIdx.x;
    const int ks  = wg & 7;
    const int cb  = (wg >> 3) & 7;
    const int rbk = wg >> 6;
    const int r0 = rbk * 64, c0 = cb * 64, kbase = ks * 64;
    const int arow = t >> 2, ac4 = t & 3;

    vf4 acc0 = {0,0,0,0}, acc1 = {0,0,0,0}, acc2 = {0,0,0,0}, acc3 = {0,0,0,0};

    for (int k0 = kbase; k0 < kbase + 64; k0 += 16) {
        vf4 a = *(const vf4*)(src + (r0 + arow) * Nn + k0 + 4 * ac4);
        vf4 b = *(const vf4*)(mat + (k0 + ty) * Nn + c0 + 4 * tx);
        __syncthreads();
        As[4*ac4+0][arow] = a.x; As[4*ac4+1][arow] = a.y;
        As[4*ac4+2][arow] = a.z; As[4*ac4+3][arow] = a.w;
        *(vf4*)&Bs[ty][4*tx] = b;
        __syncthreads();
        #pragma unroll
        for (int kk = 0; kk < 16; ++kk) {
            vf4 av = *(const vf4*)&As[kk][4*ty];
            vf4 bv = *(const vf4*)&Bs[kk][4*tx];
            acc0 += bv * av.x; acc1 += bv * av.y;
            acc2 += bv * av.z; acc3 += bv * av.w;
        }
    }
    float* yp = part + ks * (NR2 * Nn) + (r0 + 4*ty) * Nn + c0 + 4*tx;
    *(vf4*)(yp)        = acc0;
    *(vf4*)(yp + Nn)   = acc1;
    *(vf4*)(yp + 2*Nn) = acc2;
    *(vf4*)(yp + 3*Nn) = acc3;
}

// ---------------------------------------------------------------------------
// k_upd: combine 8 split-K partials (both chains) + Clenshaw step.
// ---------------------------------------------------------------------------
__global__ __launch_bounds__(256) void k_upd(
    const float* __restrict__ part, const float* __restrict__ v0,
    float* __restrict__ B1s, float* __restrict__ B2s,
    float cqj, float crj, float fscale, int finalstep)
{
    const int i = (int)blockIdx.x * 256 + threadIdx.x;   // 0..98303
    float yvq = 0.f, yvr = 0.f;
    #pragma unroll
    for (int ks = 0; ks < 8; ++ks) {
        yvq += part[ks * (NR2 * Nn) + i];
        yvr += part[ks * (NR2 * Nn) + NCr * Nn + i];
    }
    float v  = v0[i];
    float q1 = B1s[i], q2 = B2s[i];
    float r1 = B1s[i + NCr * Nn], r2 = B2s[i + NCr * Nn];
    if (!finalstep) {
        float bnq = cqj * v + fscale * yvq - 2.f * q1 - q2;
        float bnr = crj * v + fscale * yvr - 2.f * r1 - r2;
        B2s[i] = q1;              B1s[i] = bnq;
        B2s[i + NCr * Nn] = r1;   B1s[i + NCr * Nn] = bnr;
    } else {
        float Fq = cqj * v + fscale * yvq - q1 - q2;
        float Fr = crj * v + fscale * yvr - r1 - r2;
        B1s[i] = Fq;              B1s[i + NCr * Nn] = Fr;
    }
}

// ---------------------------------------------------------------------------
// k_ufin: u = Fq + sum of 8 partials of (M @ Fr).
// ---------------------------------------------------------------------------
__global__ __launch_bounds__(256) void k_ufin(
    const float* __restrict__ part, const float* __restrict__ B1s,
    float* __restrict__ u_g)
{
    const int i = (int)blockIdx.x * 256 + threadIdx.x;   // 0..98303
    float s = B1s[i];                                    // Fq
    #pragma unroll
    for (int ks = 0; ks < 8; ++ks)
        s += part[ks * (NR2 * Nn) + i];
    u_g[i] = s;
}

// ---------------------------------------------------------------------------
// k_small: su[e][j] (64 x 192): j<64 -> S[e][j] = A0[e,:]·u'[128+j,:]
//                               j>=64 -> rhs[e][j-64] = A0[e,:]·u'[j-64,:] + c[e]
// ---------------------------------------------------------------------------
__global__ __launch_bounds__(256) void k_small(
    const float* __restrict__ A0, const float* __restrict__ u,
    const float* __restrict__ c, float* __restrict__ su)
{
    __shared__ float As[16][33];
    __shared__ float Us[16][33];
    int t  = threadIdx.x;
    int tx = t & 15, ty = t >> 4;
    int e0 = ((int)blockIdx.x / 12) * 16;
    int j0 = ((int)blockIdx.x % 12) * 16;
    float acc = 0.f;

    for (int k0 = 0; k0 < Nn; k0 += 32) {
        #pragma unroll
        for (int i = 0; i < 2; ++i) {
            int ii = t + i * 256;
            int rr = ii >> 5, cc = ii & 31;
            As[rr][cc] = A0[(e0 + rr) * Nn + k0 + cc];
            int j_ = j0 + rr;
            int urow = (j_ < 64) ? (Bb + j_) : (j_ - 64);
            Us[rr][cc] = u[urow * Nn + k0 + cc];
        }
        __syncthreads();
        #pragma unroll
        for (int kk = 0; kk < 32; ++kk)
            acc += As[ty][kk] * Us[tx][kk];
        __syncthreads();
    }
    int e = e0 + ty, j = j0 + tx;
    su[e * NCr + j] = acc + ((j >= 64) ? c[e] : 0.f);
}

// ---------------------------------------------------------------------------
// k_lam3: CG on S (64x64 SPD), ONE WAVE PER COLUMN, 128 WGs x 64 thr.
// ALL state in LDS -- nothing for the register allocator to spill (k_lam2's
// srow[64] went to scratch at VGPR=48 and cost 56 us). S stored stride-65:
// bank(lane*65+k) = (lane+k)%32 -> 2-way aliasing = free (m136). pb[k] read
// is wave-uniform -> broadcast. No barriers in the CG loop (single wave,
// DS in-order). Fused correction out[b] = T_b - V^T Lambda_b.
// ---------------------------------------------------------------------------
__global__ __launch_bounds__(64) void k_lam3(
    const float* __restrict__ u_g, const float* __restrict__ su,
    float* __restrict__ out)
{
    __shared__ float Sm[64 * 65];
    __shared__ float pb[64];
    const int lane = threadIdx.x;
    const int b = (int)blockIdx.x;          // column 0..127

    // stage S (64x64) into LDS, stride 65
    #pragma unroll 8
    for (int r = 0; r < 64; ++r)
        Sm[r * 65 + lane] = su[r * NCr + lane];

    float rhs = su[lane * NCr + 64 + b];
    float xv = 0.f, rv = rhs, pv = rv;
    float rr = wred(rv * rv);

    for (int itc = 0; itc < CGIT; ++itc) {
        pb[lane] = pv;                       // single wave, DS in-order
        float q = 0.f;
        #pragma unroll
        for (int k = 0; k < 64; ++k)
            q += Sm[lane * 65 + k] * pb[k];  // conflict-free + broadcast
        float pq = wred(pv * q);
        float alpha = rr / fmaxf(pq, 1e-30f);
        xv += alpha * pv;
        rv -= alpha * q;
        float rr2 = wred(rv * rv);
        float beta = rr2 / fmaxf(rr, 1e-30f);
        rr = rr2;
        pv = rv + beta * pv;
    }
    pb[lane] = xv;                           // Lambda[:,b] broadcast in-wave

    // out[b][n] = T[b][n] - sum_e Lambda[e] * V[e][n]
    #pragma unroll
    for (int i = 0; i < 8; ++i) {
        int n = lane + 64 * i;
        float acc = u_g[b * Nn + n];
        #pragma unroll 8
        for (int e = 0; e < Ee; ++e)
            acc -= pb[e] * u_g[(Bb + e) * Nn + n];
        out[b * Nn + n] = acc;
    }
}

// ---------------------------------------------------------------------------
extern "C" void kernel_launch(void* const* d_in, const int* in_sizes, int n_in,
                              void* d_out, int out_size, void* d_ws, size_t ws_size,
                              hipStream_t stream)
{
    const float* x     = (const float*)d_in[0];
    const float* parms = (const float*)d_in[1];
    const float* Mm    = (const float*)d_in[2];
    const float* A0    = (const float*)d_in[3];
    // d_in[4] = B0 unused (F at zeros -> only c survives)
    const float* c     = (const float*)d_in[5];
    float* out = (float*)d_out;

    float* ws    = (float*)d_ws;
    float* Ypart = ws;                                   // 8 * 512*512
    float* Y     = Ypart + 8 * Nn * Nn;                  // 512*512
    float* Zpart = Y + Nn * Nn;                          // 8 * 384*512
    float* v0    = Zpart + 8 * NR2 * Nn;                 // 192*512
    float* B1s   = v0 + NCr * Nn;                        // 384*512
    float* B2s   = B1s + NR2 * Nn;                       // 384*512
    float* u_g   = B2s + NR2 * Nn;                       // 192*512
    float* su    = u_g + NCr * Nn;                       // 64*192

    // ---- host: degree-9 Chebyshev poly for 1/h on [1, 3.12], even/odd split,
    // converted to Chebyshev basis on y = m^2 in [0, ymax] (all double).
    const double aa = 1.0, bbound = 3.12;
    const double th = 0.5 * (bbound + aa), de = 0.5 * (bbound - aa), sg = th / de;
    double rp[16] = {0}, dp[16] = {0}, xp[16] = {0}, hd[16];
    rp[0] = 1.0; dp[0] = 1.0 / th; xp[0] = 1.0 / th;
    double rho_prev = 1.0 / sg;
    for (int k = 1; k <= 9; ++k) {
        double rho = 1.0 / (2.0 * sg - rho_prev);
        double C1 = rho * rho_prev, C2 = 2.0 * rho / de;
        for (int i = 15; i >= 1; --i) hd[i] = dp[i - 1];
        hd[0] = 0.0;
        for (int i = 0; i < 16; ++i) {
            rp[i] -= hd[i];
            dp[i] = C1 * dp[i] + C2 * rp[i];
            xp[i] += dp[i];
        }
        rho_prev = rho;
    }
    // substitute h = 1 + m/2
    double pm[16] = {0};
    for (int k = 0; k <= 9; ++k) {
        double term[16] = {0}; term[0] = 1.0;
        for (int e = 0; e < k; ++e) {
            double nt[16] = {0};
            for (int i = 0; i <= e; ++i) { nt[i] += term[i]; nt[i + 1] += 0.5 * term[i]; }
            for (int i = 0; i <= e + 1; ++i) term[i] = nt[i];
        }
        for (int i = 0; i <= k; ++i) pm[i] += xp[k] * term[i];
    }
    double qm[8] = {0}, rm[8] = {0};
    for (int jj = 0; jj < 5; ++jj) { qm[jj] = pm[2 * jj]; rm[jj] = pm[2 * jj + 1]; }
    const double mmax = 2.0 * (bbound - 1.0);
    const double ymax = mmax * mmax;
    double cq[5] = {0}, cr[5] = {0};
    const int NP = 64;
    for (int i = 0; i < NP; ++i) {
        double thn = M_PI * (i + 0.5) / NP;
        double s = cos(thn);
        double y = 0.5 * ymax * (s + 1.0);
        double vq = 0, vr = 0;
        for (int d2 = 4; d2 >= 0; --d2) { vq = vq * y + qm[d2]; vr = vr * y + rm[d2]; }
        for (int jj = 0; jj < 5; ++jj) {
            cq[jj] += (2.0 / NP) * vq * cos(jj * thn);
            cr[jj] += (2.0 / NP) * vr * cos(jj * thn);
        }
    }
    cq[0] *= 0.5; cr[0] *= 0.5;
    CCoef cf;
    for (int jj = 0; jj < 5; ++jj) { cf.cq[jj] = (float)cq[jj]; cf.cr[jj] = (float)cr[jj]; }
    cf.f4 = (float)(4.0 / ymax);
    cf.f2 = (float)(2.0 / ymax);

    // ---- launch chain (graph-captured): everything full-chip, no grid syncs
    hipLaunchKernelGGL(k_prep2, dim3(512), dim3(256), 0, stream, Mm, Ypart);
    hipLaunchKernelGGL(k_red,   dim3(256), dim3(256), 0, stream, Ypart, Y);
    hipLaunchKernelGGL(k_build, dim3(384), dim3(256), 0, stream,
                       x, parms, A0, v0, B1s, B2s, cf.cq[4], cf.cr[4]);

    for (int step = 0; step < 4; ++step) {
        hipLaunchKernelGGL(k_ymul, dim3(NR2 / 64 * 64), dim3(256), 0, stream,
                           B1s, Y, Zpart);
        if (step < 3) {
            hipLaunchKernelGGL(k_upd, dim3(384), dim3(256), 0, stream,
                               Zpart, v0, B1s, B2s,
                               cf.cq[3 - step], cf.cr[3 - step], cf.f4, 0);
        } else {
            hipLaunchKernelGGL(k_upd, dim3(384), dim3(256), 0, stream,
                               Zpart, v0, B1s, B2s,
                               cf.cq[0], cf.cr[0], cf.f2, 1);
        }
    }

    // final M-pass on Fr (rows 192..384 of B1s), then u = Fq + M*Fr
    hipLaunchKernelGGL(k_ymul, dim3(192), dim3(256), 0, stream,
                       B1s + NCr * Nn, Mm, Zpart);
    hipLaunchKernelGGL(k_ufin, dim3(384), dim3(256), 0, stream, Zpart, B1s, u_g);

    hipLaunchKernelGGL(k_small, dim3(48), dim3(256), 0, stream, A0, u_g, c, su);
    hipLaunchKernelGGL(k_lam3,  dim3(128), dim3(64), 0, stream, u_g, su, out);
}